// Round 3
// baseline (3909.734 us; speedup 1.0000x reference)
//
#include <hip/hip_runtime.h>
#include <hip/hip_bf16.h>

// PointerNetwork: B=4096, L=10, IN=8, H=512, W=512. All tensors fp32
// (reference is jnp.float32; round-1 NaN proved device buffers are fp32).
//
// Math simplification: log_softmax over size-1 axes => attnd==attnc==0
// => hi==he==0. Surviving compute:
//   enc GRU (xg via folded emb, hg), ew3 = h_l @ w3^T,
//   dec GRU, a4 = h_t @ w4^T,
//   probs_seq[b,t,l] = sum_w tanh(ew3[b,l,w] + a4[b,w]) * v2[w]
//   probs_ori[b,t,:] = h_t @ wori[:, H:2H]^T + bori

#define B_   4096
#define L_   10
#define IN_  8
#define H_   512
#define H3_  1536
#define W_   512
#define ORI_BASE (B_ * L_ * L_)   // 409600

__device__ __forceinline__ float sigmoid_(float x) { return 1.f / (1.f + __expf(-x)); }
__device__ __forceinline__ float tanh_(float x) {
  float cx = fminf(fmaxf(x, -15.f), 15.f);
  float e = __expf(2.f * cx);
  return (e - 1.f) / (e + 1.f);
}

// Fold embedding into encoder input weight:
//   Wc[g,j] = sum_k enc_wih[g,k] * emb_w[k,j]   (j < 8)
//   bc[g]   = sum_k enc_wih[g,k] * emb_b[k] + enc_bih[g]
__global__ __launch_bounds__(256) void build_wc(
    const float* __restrict__ enc_wih, const float* __restrict__ emb_w,
    const float* __restrict__ emb_b, const float* __restrict__ enc_bih,
    float* __restrict__ Wc, float* __restrict__ bc)
{
  int idx = blockIdx.x * 256 + threadIdx.x;
  if (idx >= H3_ * 9) return;
  int g = idx / 9, j = idx - g * 9;
  const float* wr = enc_wih + (long)g * H_;
  float acc = 0.f;
  if (j < IN_) {
    for (int k = 0; k < H_; ++k) acc += wr[k] * emb_w[k * IN_ + j];
    Wc[g * IN_ + j] = acc;
  } else {
    for (int k = 0; k < H_; ++k) acc += wr[k] * emb_b[k];
    bc[g] = acc + enc_bih[g];
  }
}

// C[M,N] = A[M,K] @ B[N,K]^T (+bias). 64x64 tile, BK=16, 256 thr, 4x4 micro.
// Grid: x = N/64, y = M/64. M,N multiples of 64.
__global__ __launch_bounds__(256) void gemm_nt(
    const float* __restrict__ A, long lda, long aoff,
    const float* __restrict__ Bw,
    const float* __restrict__ bias,
    float* __restrict__ C, long ldc, long coff,
    int K)
{
  __shared__ float As[16][68];
  __shared__ float Bs[16][68];
  const int tid = threadIdx.x;
  const int tx = tid & 15, ty = tid >> 4;
  const long row0 = (long)blockIdx.y * 64;
  const long col0 = (long)blockIdx.x * 64;
  float acc[4][4] = {};

  for (int k0 = 0; k0 < K; k0 += 16) {
#pragma unroll
    for (int i = 0; i < 4; ++i) {
      int idx = i * 256 + tid;
      int m = idx >> 4, kk = idx & 15;
      float av = 0.f, bv = 0.f;
      if (k0 + kk < K) {
        av = A[aoff + (row0 + m) * lda + k0 + kk];
        bv = Bw[(col0 + m) * (long)K + k0 + kk];
      }
      As[kk][m] = av;
      Bs[kk][m] = bv;
    }
    __syncthreads();
#pragma unroll
    for (int kk = 0; kk < 16; ++kk) {
      float a[4], b[4];
#pragma unroll
      for (int i = 0; i < 4; ++i) a[i] = As[kk][ty * 4 + i];
#pragma unroll
      for (int j = 0; j < 4; ++j) b[j] = Bs[kk][tx * 4 + j];
#pragma unroll
      for (int i = 0; i < 4; ++i)
#pragma unroll
        for (int j = 0; j < 4; ++j) acc[i][j] += a[i] * b[j];
    }
    __syncthreads();
  }

#pragma unroll
  for (int i = 0; i < 4; ++i) {
    long r = row0 + ty * 4 + i;
#pragma unroll
    for (int j = 0; j < 4; ++j) {
      long c = col0 + tx * 4 + j;
      float v = acc[i][j];
      if (bias) v += bias[c];
      C[coff + r * ldc + c] = v;
    }
  }
}

// GRU gate: h updated in place from xg,hg (B,3H). Exactly B*H threads.
__global__ __launch_bounds__(256) void gru_gate(
    const float* __restrict__ xg, const float* __restrict__ hg,
    float* __restrict__ h)
{
  int idx = blockIdx.x * 256 + threadIdx.x;
  int b = idx >> 9;
  long g = (long)b * H3_ + (idx & 511);
  float xr = xg[g], xz = xg[g + 512], xn = xg[g + 1024];
  float hr = hg[g], hz = hg[g + 512], hn = hg[g + 1024];
  float r = sigmoid_(xr + hr);
  float z = sigmoid_(xz + hz);
  float n = tanh_(xn + r * hn);
  h[idx] = (1.f - z) * n + z * h[idx];
}

// probs_seq[b,t,l] = sum_w tanh(ew3[b,l,w] + a4[b,w]) * v2[w]; one wave per (b,l).
__global__ __launch_bounds__(256) void out_seq_k(
    const float* __restrict__ ew3,   // (B, L, W)
    const float* __restrict__ a4,    // (B, W)
    const float* __restrict__ v2,
    float* __restrict__ out, int t)
{
  int wid = (blockIdx.x * 256 + threadIdx.x) >> 6;   // b*L + l
  int lane = threadIdx.x & 63;
  int b = wid / L_, l = wid - b * L_;
  const float* ew = ew3 + ((long)b * L_ + l) * W_;
  const float* ar = a4 + (long)b * W_;
  float acc = 0.f;
  for (int w = lane; w < W_; w += 64)
    acc += tanh_(ew[w] + ar[w]) * v2[w];
#pragma unroll
  for (int off = 32; off; off >>= 1) acc += __shfl_down(acc, off, 64);
  if (lane == 0) out[((long)b * L_ + t) * L_ + l] = acc;
}

// probs_ori[b,t,o] = sum_k h[b,k] * wori[o, 512+k] + bori[o]; one thread per (b,o).
__global__ __launch_bounds__(256) void out_ori_k(
    const float* __restrict__ h, const float* __restrict__ wori,
    const float* __restrict__ bori, float* __restrict__ out, int t)
{
  int idx = blockIdx.x * 256 + threadIdx.x;
  int b = idx / 6, o = idx - b * 6;
  const float* wr = wori + (long)o * H3_ + H_;
  const float* hr = h + (long)b * H_;
  float acc = 0.f;
  for (int k = 0; k < H_; ++k) acc += hr[k] * wr[k];
  out[ORI_BASE + ((long)b * L_ + t) * 6 + o] = acc + bori[o];
}

extern "C" void kernel_launch(void* const* d_in, const int* in_sizes, int n_in,
                              void* d_out, int out_size, void* d_ws, size_t ws_size,
                              hipStream_t stream)
{
  const float* items   = (const float*)d_in[0];
  const float* dec_in  = (const float*)d_in[1];
  const float* emb_w   = (const float*)d_in[2];
  const float* emb_b   = (const float*)d_in[3];
  const float* enc_wih = (const float*)d_in[4];
  const float* enc_whh = (const float*)d_in[5];
  const float* enc_bih = (const float*)d_in[6];
  const float* enc_bhh = (const float*)d_in[7];
  const float* dec_wih = (const float*)d_in[8];
  const float* dec_whh = (const float*)d_in[9];
  const float* dec_bih = (const float*)d_in[10];
  const float* dec_bhh = (const float*)d_in[11];
  const float* w3      = (const float*)d_in[14];
  const float* w4      = (const float*)d_in[15];
  const float* v2      = (const float*)d_in[20];
  const float* wori    = (const float*)d_in[23];
  const float* bori    = (const float*)d_in[24];
  float* out = (float*)d_out;

  // Workspace (fp32, ~136 MB; round-1 kernel proved >=143 MB available):
  char* ws = (char*)d_ws;
  size_t off = 0;
  auto alloc = [&](size_t bytes) { size_t o = off; off += (bytes + 255) & ~255UL; return o; };
  float* Wc  = (float*)(ws + alloc(H3_ * IN_ * 4));
  float* bc  = (float*)(ws + alloc(H3_ * 4));
  float* h   = (float*)(ws + alloc((size_t)B_ * H_ * 4));
  float* xg  = (float*)(ws + alloc((size_t)B_ * H3_ * 4));
  float* hg  = (float*)(ws + alloc((size_t)B_ * H3_ * 4));
  float* a4  = hg;   // alias: hg is dead when a4 is live
  float* ew3 = (float*)(ws + alloc((size_t)B_ * L_ * W_ * 4));

  build_wc<<<(H3_ * 9 + 255) / 256, 256, 0, stream>>>(
      enc_wih, emb_w, emb_b, enc_bih, Wc, bc);

  hipMemsetAsync(h, 0, (size_t)B_ * H_ * 4, stream);

  // ---- Encoder: 10 steps ----
  for (int t = 0; t < L_; ++t) {
    // xg_t = items[:,t,:] @ Wc^T + bc   (K=8, emb folded in)
    gemm_nt<<<dim3(24, 64), 256, 0, stream>>>(
        items, (long)L_ * IN_, (long)t * IN_, Wc, bc, xg, H3_, 0, IN_);
    // hg = h @ enc_whh^T + enc_bhh      (K=512)
    gemm_nt<<<dim3(24, 64), 256, 0, stream>>>(
        h, H_, 0, enc_whh, enc_bhh, hg, H3_, 0, H_);
    gru_gate<<<(B_ * H_) / 256, 256, 0, stream>>>(xg, hg, h);
    // ew3[:,t,:] = h @ w3^T  (layout (b,l,w))
    gemm_nt<<<dim3(8, 64), 256, 0, stream>>>(
        h, H_, 0, w3, nullptr, ew3, (long)L_ * W_, (long)t * W_, H_);
  }

  // xg_dec = dec_in @ dec_wih^T + dec_bih (fixed across decoder steps)
  gemm_nt<<<dim3(24, 64), 256, 0, stream>>>(
      dec_in, H_, 0, dec_wih, dec_bih, xg, H3_, 0, H_);

  // ---- Decoder: 10 steps (h carries over = h0) ----
  for (int t = 0; t < L_; ++t) {
    gemm_nt<<<dim3(24, 64), 256, 0, stream>>>(
        h, H_, 0, dec_whh, dec_bhh, hg, H3_, 0, H_);
    gru_gate<<<(B_ * H_) / 256, 256, 0, stream>>>(xg, hg, h);
    // a4 = h @ w4^T (aliases hg, dead until next step)
    gemm_nt<<<dim3(8, 64), 256, 0, stream>>>(
        h, H_, 0, w4, nullptr, a4, W_, 0, H_);
    out_seq_k<<<(B_ * L_) / 4, 256, 0, stream>>>(ew3, a4, v2, out, t);
    out_ori_k<<<(B_ * 6) / 256, 256, 0, stream>>>(h, wori, bori, out, t);
  }
}

// Round 4
// 1693.865 us; speedup vs baseline: 2.3082x; 2.3082x over previous
//
#include <hip/hip_runtime.h>
#include <hip/hip_bf16.h>

// PointerNetwork: B=4096, L=10, IN=8, H=512, W=512. fp32 in/out.
// log_softmax over size-1 axes => hi==he==0. Surviving compute:
//   enc GRU (xg via folded emb K=8, hg K=512), ew3 = h_l @ w3^T,
//   dec GRU, a4 = h_t @ w4^T, out_seq = tanh(ew3+a4)@v2,
//   out_ori = h_t @ wori[:,H:2H]^T + bori.
// Round 4: all K=512 GEMMs on bf16 MFMA (m97 structure: 128x128 tile,
// BK=32, global_load_lds width=16, 16x16x32 MFMA). fp32 master h +
// bf16 shadow for MFMA A-operand. ew3 stored bf16.

#define B_   4096
#define L_   10
#define IN_  8
#define H_   512
#define H3_  1536
#define W_   512
#define ORI_BASE (B_ * L_ * L_)   // 409600

typedef __attribute__((ext_vector_type(8))) short s8v;
typedef __attribute__((ext_vector_type(4))) float f4v;

__device__ __forceinline__ float sigmoid_(float x) { return 1.f / (1.f + __expf(-x)); }
__device__ __forceinline__ float tanh_(float x) {
  float cx = fminf(fmaxf(x, -15.f), 15.f);
  float e = __expf(2.f * cx);
  return (e - 1.f) / (e + 1.f);
}
__device__ __forceinline__ short f2bf(float f) {
  __hip_bfloat16 h = __float2bfloat16(f);
  return __builtin_bit_cast(short, h);
}
__device__ __forceinline__ float bf2f(short s) {
  __hip_bfloat16 h = __builtin_bit_cast(__hip_bfloat16, s);
  return __bfloat162float(h);
}
__device__ __forceinline__ void stc(float* p, float v) { *p = v; }
__device__ __forceinline__ void stc(short* p, float v) { *p = f2bf(v); }

// ---- fp32 -> bf16(short) convert ----
__global__ __launch_bounds__(256) void f2bf_k(const float* __restrict__ src,
                                              short* __restrict__ dst, int n)
{
  int i = blockIdx.x * 256 + threadIdx.x;
  if (i < n) dst[i] = f2bf(src[i]);
}

// ---- fold embedding into encoder input weight (fp32) ----
__global__ __launch_bounds__(256) void build_wc(
    const float* __restrict__ enc_wih, const float* __restrict__ emb_w,
    const float* __restrict__ emb_b, const float* __restrict__ enc_bih,
    float* __restrict__ Wc, float* __restrict__ bc)
{
  int idx = blockIdx.x * 256 + threadIdx.x;
  if (idx >= H3_ * 9) return;
  int g = idx / 9, j = idx - g * 9;
  const float* wr = enc_wih + (long)g * H_;
  float acc = 0.f;
  if (j < IN_) {
    for (int k = 0; k < H_; ++k) acc += wr[k] * emb_w[k * IN_ + j];
    Wc[g * IN_ + j] = acc;
  } else {
    for (int k = 0; k < H_; ++k) acc += wr[k] * emb_b[k];
    bc[g] = acc + enc_bih[g];
  }
}

// ---- fp32 vector GEMM (only for K=8 xg): C[M,N]=A@B^T+bias ----
__global__ __launch_bounds__(256) void gemm_nt(
    const float* __restrict__ A, long lda, long aoff,
    const float* __restrict__ Bw,
    const float* __restrict__ bias,
    float* __restrict__ C, long ldc, long coff,
    int K)
{
  __shared__ float As[16][68];
  __shared__ float Bs[16][68];
  const int tid = threadIdx.x;
  const int tx = tid & 15, ty = tid >> 4;
  const long row0 = (long)blockIdx.y * 64;
  const long col0 = (long)blockIdx.x * 64;
  float acc[4][4] = {};
  for (int k0 = 0; k0 < K; k0 += 16) {
#pragma unroll
    for (int i = 0; i < 4; ++i) {
      int idx = i * 256 + tid;
      int m = idx >> 4, kk = idx & 15;
      float av = 0.f, bv = 0.f;
      if (k0 + kk < K) {
        av = A[aoff + (row0 + m) * lda + k0 + kk];
        bv = Bw[(col0 + m) * (long)K + k0 + kk];
      }
      As[kk][m] = av;
      Bs[kk][m] = bv;
    }
    __syncthreads();
#pragma unroll
    for (int kk = 0; kk < 16; ++kk) {
      float a[4], b[4];
#pragma unroll
      for (int i = 0; i < 4; ++i) a[i] = As[kk][ty * 4 + i];
#pragma unroll
      for (int j = 0; j < 4; ++j) b[j] = Bs[kk][tx * 4 + j];
#pragma unroll
      for (int i = 0; i < 4; ++i)
#pragma unroll
        for (int j = 0; j < 4; ++j) acc[i][j] += a[i] * b[j];
    }
    __syncthreads();
  }
#pragma unroll
  for (int i = 0; i < 4; ++i) {
    long r = row0 + ty * 4 + i;
#pragma unroll
    for (int j = 0; j < 4; ++j) {
      long c = col0 + tx * 4 + j;
      float v = acc[i][j];
      if (bias) v += bias[c];
      C[coff + r * ldc + c] = v;
    }
  }
}

// ---- bf16 MFMA GEMM: C[M,N] = A[M,K] @ B[N,K]^T (+bias). ----
// 128x128 tile, BK=32, 256 thr (4 waves in 2x2), 4x4 16x16x32 MFMAs/wave.
// A,B bf16 (as short), row-major along K. M,N % 128 == 0, K % 32 == 0.
// CT = float (fp32 out) or short (bf16 out).
template <typename CT>
__global__ __launch_bounds__(256) void gemm_bf16(
    const short* __restrict__ A, long lda,
    const short* __restrict__ Bw, long ldb,
    const float* __restrict__ bias,
    CT* __restrict__ C, long ldc, long coff, int K)
{
  __shared__ short As[128 * 32];
  __shared__ short Bs[128 * 32];
  const int tid = threadIdx.x;
  const long row0 = (long)blockIdx.y * 128;
  const long col0 = (long)blockIdx.x * 128;
  const int wave = tid >> 6, lane = tid & 63;
  const int wm = (wave & 1) * 64, wn = (wave >> 1) * 64;
  const int r16 = lane & 15, quad = lane >> 4;

  f4v acc[4][4] = {};

  for (int k0 = 0; k0 < K; k0 += 32) {
#pragma unroll
    for (int r = 0; r < 2; ++r) {
      int idx = r * 256 + tid;            // 0..511
      int m = idx >> 2;                   // tile row 0..127
      int k8 = (idx & 3) * 8;             // 0,8,16,24
      __builtin_amdgcn_global_load_lds(
          (const __attribute__((address_space(1))) void*)(A + (row0 + m) * lda + k0 + k8),
          (__attribute__((address_space(3))) void*)(As + idx * 8), 16, 0, 0);
      __builtin_amdgcn_global_load_lds(
          (const __attribute__((address_space(1))) void*)(Bw + (col0 + m) * ldb + k0 + k8),
          (__attribute__((address_space(3))) void*)(Bs + idx * 8), 16, 0, 0);
    }
    __syncthreads();
    s8v af[4], bf[4];
#pragma unroll
    for (int i = 0; i < 4; ++i)
      af[i] = *(const s8v*)&As[(wm + i * 16 + r16) * 32 + quad * 8];
#pragma unroll
    for (int j = 0; j < 4; ++j)
      bf[j] = *(const s8v*)&Bs[(wn + j * 16 + r16) * 32 + quad * 8];
#pragma unroll
    for (int i = 0; i < 4; ++i)
#pragma unroll
      for (int j = 0; j < 4; ++j)
        acc[i][j] = __builtin_amdgcn_mfma_f32_16x16x32_bf16(af[i], bf[j], acc[i][j], 0, 0, 0);
    __syncthreads();
  }

  // C/D layout: col = lane&15, row = quad*4 + reg (m89/m91-verified).
#pragma unroll
  for (int i = 0; i < 4; ++i) {
    long rbase = row0 + wm + i * 16 + quad * 4;
#pragma unroll
    for (int j = 0; j < 4; ++j) {
      long c = col0 + wn + j * 16 + r16;
      float bv = bias ? bias[c] : 0.f;
#pragma unroll
      for (int rg = 0; rg < 4; ++rg)
        stc(&C[coff + (rbase + rg) * ldc + c], acc[i][j][rg] + bv);
    }
  }
}

// ---- GRU gate: update fp32 master h and bf16 shadow hb. B*H threads. ----
__global__ __launch_bounds__(256) void gru_gate(
    const float* __restrict__ xg, const float* __restrict__ hg,
    float* __restrict__ h, short* __restrict__ hb)
{
  int idx = blockIdx.x * 256 + threadIdx.x;
  int b = idx >> 9;
  long g = (long)b * H3_ + (idx & 511);
  float xr = xg[g], xz = xg[g + 512], xn = xg[g + 1024];
  float hr = hg[g], hz = hg[g + 512], hn = hg[g + 1024];
  float r = sigmoid_(xr + hr);
  float z = sigmoid_(xz + hz);
  float n = tanh_(xn + r * hn);
  float hv = (1.f - z) * n + z * h[idx];
  h[idx] = hv;
  hb[idx] = f2bf(hv);
}

// ---- probs_seq[b,t,l] = sum_w tanh(ew3[b,l,w] + a4[b,w]) * v2[w] ----
__global__ __launch_bounds__(256) void out_seq_k(
    const short* __restrict__ ew3,   // (B, L, W) bf16
    const float* __restrict__ a4,    // (B, W)
    const float* __restrict__ v2,
    float* __restrict__ out, int t)
{
  int wid = (blockIdx.x * 256 + threadIdx.x) >> 6;   // b*L + l
  int lane = threadIdx.x & 63;
  int b = wid / L_, l = wid - b * L_;
  const short* ew = ew3 + ((long)b * L_ + l) * W_;
  const float* ar = a4 + (long)b * W_;
  float acc = 0.f;
  for (int w = lane; w < W_; w += 64)
    acc += tanh_(bf2f(ew[w]) + ar[w]) * v2[w];
#pragma unroll
  for (int off = 32; off; off >>= 1) acc += __shfl_down(acc, off, 64);
  if (lane == 0) out[((long)b * L_ + t) * L_ + l] = acc;
}

// ---- probs_ori[b,t,o] = h[b,:] . wori[o, H:2H] + bori[o] ----
__global__ __launch_bounds__(256) void out_ori_k(
    const float* __restrict__ h, const float* __restrict__ wori,
    const float* __restrict__ bori, float* __restrict__ out, int t)
{
  int idx = blockIdx.x * 256 + threadIdx.x;
  int b = idx / 6, o = idx - b * 6;
  const float* wr = wori + (long)o * H3_ + H_;
  const float* hr = h + (long)b * H_;
  float acc = 0.f;
  for (int k = 0; k < H_; ++k) acc += hr[k] * wr[k];
  out[ORI_BASE + ((long)b * L_ + t) * 6 + o] = acc + bori[o];
}

extern "C" void kernel_launch(void* const* d_in, const int* in_sizes, int n_in,
                              void* d_out, int out_size, void* d_ws, size_t ws_size,
                              hipStream_t stream)
{
  const float* items   = (const float*)d_in[0];
  const float* dec_in  = (const float*)d_in[1];
  const float* emb_w   = (const float*)d_in[2];
  const float* emb_b   = (const float*)d_in[3];
  const float* enc_wih = (const float*)d_in[4];
  const float* enc_whh = (const float*)d_in[5];
  const float* enc_bih = (const float*)d_in[6];
  const float* enc_bhh = (const float*)d_in[7];
  const float* dec_wih = (const float*)d_in[8];
  const float* dec_whh = (const float*)d_in[9];
  const float* dec_bih = (const float*)d_in[10];
  const float* dec_bhh = (const float*)d_in[11];
  const float* w3      = (const float*)d_in[14];
  const float* w4      = (const float*)d_in[15];
  const float* v2      = (const float*)d_in[20];
  const float* wori    = (const float*)d_in[23];
  const float* bori    = (const float*)d_in[24];
  float* out = (float*)d_out;

  // Workspace (~106 MB; >=136 MB proven available in round 2/3):
  char* ws = (char*)d_ws;
  size_t off = 0;
  auto alloc = [&](size_t bytes) { size_t o = off; off += (bytes + 255) & ~255UL; return o; };
  float* Wc    = (float*)(ws + alloc(H3_ * IN_ * 4));
  float* bc    = (float*)(ws + alloc(H3_ * 4));
  float* h     = (float*)(ws + alloc((size_t)B_ * H_ * 4));     // 8 MB
  short* hb    = (short*)(ws + alloc((size_t)B_ * H_ * 2));     // 4 MB
  float* xg    = (float*)(ws + alloc((size_t)B_ * H3_ * 4));    // 24 MB
  float* hg    = (float*)(ws + alloc((size_t)B_ * H3_ * 4));    // 24 MB
  float* a4    = hg;   // alias: hg dead when a4 live
  short* ew3   = (short*)(ws + alloc((size_t)B_ * L_ * W_ * 2));// 40 MB
  short* whh_e = (short*)(ws + alloc((size_t)H3_ * H_ * 2));
  short* whh_d = (short*)(ws + alloc((size_t)H3_ * H_ * 2));
  short* wih_d = (short*)(ws + alloc((size_t)H3_ * H_ * 2));
  short* w3b   = (short*)(ws + alloc((size_t)W_ * H_ * 2));
  short* w4b   = (short*)(ws + alloc((size_t)W_ * H_ * 2));
  short* decb  = (short*)(ws + alloc((size_t)B_ * H_ * 2));     // 4 MB

  // ---- weight / input conversions to bf16 ----
  f2bf_k<<<(H3_ * H_ + 255) / 256, 256, 0, stream>>>(enc_whh, whh_e, H3_ * H_);
  f2bf_k<<<(H3_ * H_ + 255) / 256, 256, 0, stream>>>(dec_whh, whh_d, H3_ * H_);
  f2bf_k<<<(H3_ * H_ + 255) / 256, 256, 0, stream>>>(dec_wih, wih_d, H3_ * H_);
  f2bf_k<<<(W_ * H_ + 255) / 256, 256, 0, stream>>>(w3, w3b, W_ * H_);
  f2bf_k<<<(W_ * H_ + 255) / 256, 256, 0, stream>>>(w4, w4b, W_ * H_);
  f2bf_k<<<(B_ * H_ + 255) / 256, 256, 0, stream>>>(dec_in, decb, B_ * H_);

  build_wc<<<(H3_ * 9 + 255) / 256, 256, 0, stream>>>(
      enc_wih, emb_w, emb_b, enc_bih, Wc, bc);

  hipMemsetAsync(h, 0, (size_t)B_ * H_ * 4, stream);
  hipMemsetAsync(hb, 0, (size_t)B_ * H_ * 2, stream);

  // ---- Encoder: 10 steps ----
  for (int t = 0; t < L_; ++t) {
    // xg_t = items[:,t,:] @ Wc^T + bc   (K=8, fp32 vector GEMM)
    gemm_nt<<<dim3(24, 64), 256, 0, stream>>>(
        items, (long)L_ * IN_, (long)t * IN_, Wc, bc, xg, H3_, 0, IN_);
    // hg = h @ enc_whh^T + enc_bhh      (MFMA)
    gemm_bf16<float><<<dim3(12, 32), 256, 0, stream>>>(
        hb, H_, whh_e, H_, enc_bhh, hg, H3_, 0, H_);
    gru_gate<<<(B_ * H_) / 256, 256, 0, stream>>>(xg, hg, h, hb);
    // ew3[:,t,:] = h @ w3^T  (MFMA, bf16 out, layout (b,l,w))
    gemm_bf16<short><<<dim3(4, 32), 256, 0, stream>>>(
        hb, H_, w3b, H_, nullptr, ew3, (long)L_ * W_, (long)t * W_, H_);
  }

  // xg_dec = dec_in @ dec_wih^T + dec_bih (MFMA, fixed across decoder steps)
  gemm_bf16<float><<<dim3(12, 32), 256, 0, stream>>>(
      decb, H_, wih_d, H_, dec_bih, xg, H3_, 0, H_);

  // ---- Decoder: 10 steps (h carries over = h0) ----
  for (int t = 0; t < L_; ++t) {
    gemm_bf16<float><<<dim3(12, 32), 256, 0, stream>>>(
        hb, H_, whh_d, H_, dec_bhh, hg, H3_, 0, H_);
    gru_gate<<<(B_ * H_) / 256, 256, 0, stream>>>(xg, hg, h, hb);
    // a4 = h @ w4^T (MFMA; aliases hg, dead until next step)
    gemm_bf16<float><<<dim3(4, 32), 256, 0, stream>>>(
        hb, H_, w4b, H_, nullptr, a4, W_, 0, H_);
    out_seq_k<<<(B_ * L_) / 4, 256, 0, stream>>>(ew3, a4, v2, out, t);
    out_ori_k<<<(B_ * 6) / 256, 256, 0, stream>>>(h, wori, bori, out, t);
  }
}

// Round 5
// 1111.044 us; speedup vs baseline: 3.5190x; 1.5246x over previous
//
#include <hip/hip_runtime.h>
#include <hip/hip_bf16.h>

// PointerNetwork: B=4096, L=10, IN=8, H=512, W=512. fp32 in/out, ws=256MiB.
// log_softmax over size-1 axes => hi==he==0. Surviving compute:
//   enc GRU, ew3 = h_enc @ w3^T, dec GRU, a4 = h_dec @ w4^T,
//   out_seq = tanh(ew3+a4)@v2, out_ori = h_dec @ wori[:,H:2H]^T + bori.
// Round 5: (1) GRU gate fused into hh-MFMA epilogue (3-gate 64x128 tile,
// no hg buffer); (2) bf16 h-history stored per step, ew3/a4/out_seq/out_ori
// batched into single launches after the recurrences. 44 launches total.

#define B_   4096
#define L_   10
#define IN_  8
#define H_   512
#define H3_  1536
#define W_   512
#define ORI_BASE (B_ * L_ * L_)   // 409600

typedef __attribute__((ext_vector_type(8))) short s8v;
typedef __attribute__((ext_vector_type(4))) float f4v;

__device__ __forceinline__ float sigmoid_(float x) { return 1.f / (1.f + __expf(-x)); }
__device__ __forceinline__ float tanh_(float x) {
  float cx = fminf(fmaxf(x, -15.f), 15.f);
  float e = __expf(2.f * cx);
  return (e - 1.f) / (e + 1.f);
}
__device__ __forceinline__ short f2bf(float f) {
  __hip_bfloat16 h = __float2bfloat16(f);
  return __builtin_bit_cast(short, h);
}
__device__ __forceinline__ float bf2f(short s) {
  __hip_bfloat16 h = __builtin_bit_cast(__hip_bfloat16, s);
  return __bfloat162float(h);
}
__device__ __forceinline__ void stc(float* p, float v) { *p = v; }
__device__ __forceinline__ void stc(short* p, float v) { *p = f2bf(v); }

__global__ __launch_bounds__(256) void f2bf_k(const float* __restrict__ src,
                                              short* __restrict__ dst, int n)
{
  int i = blockIdx.x * 256 + threadIdx.x;
  if (i < n) dst[i] = f2bf(src[i]);
}

// fold embedding into encoder input weight (fp32)
__global__ __launch_bounds__(256) void build_wc(
    const float* __restrict__ enc_wih, const float* __restrict__ emb_w,
    const float* __restrict__ emb_b, const float* __restrict__ enc_bih,
    float* __restrict__ Wc, float* __restrict__ bc)
{
  int idx = blockIdx.x * 256 + threadIdx.x;
  if (idx >= H3_ * 9) return;
  int g = idx / 9, j = idx - g * 9;
  const float* wr = enc_wih + (long)g * H_;
  float acc = 0.f;
  if (j < IN_) {
    for (int k = 0; k < H_; ++k) acc += wr[k] * emb_w[k * IN_ + j];
    Wc[g * IN_ + j] = acc;
  } else {
    for (int k = 0; k < H_; ++k) acc += wr[k] * emb_b[k];
    bc[g] = acc + enc_bih[g];
  }
}

// fp32 vector GEMM for K=8 xg: C[M,N]=A@B^T+bias. 64x64 tile.
__global__ __launch_bounds__(256) void gemm_nt(
    const float* __restrict__ A, long lda, long aoff,
    const float* __restrict__ Bw,
    const float* __restrict__ bias,
    float* __restrict__ C, long ldc, int K)
{
  __shared__ float As[16][68];
  __shared__ float Bs[16][68];
  const int tid = threadIdx.x;
  const int tx = tid & 15, ty = tid >> 4;
  const long row0 = (long)blockIdx.y * 64;
  const long col0 = (long)blockIdx.x * 64;
  float acc[4][4] = {};
  for (int k0 = 0; k0 < K; k0 += 16) {
#pragma unroll
    for (int i = 0; i < 4; ++i) {
      int idx = i * 256 + tid;
      int m = idx >> 4, kk = idx & 15;
      float av = 0.f, bv = 0.f;
      if (k0 + kk < K) {
        av = A[aoff + (row0 + m) * lda + k0 + kk];
        bv = Bw[(col0 + m) * (long)K + k0 + kk];
      }
      As[kk][m] = av;
      Bs[kk][m] = bv;
    }
    __syncthreads();
#pragma unroll
    for (int kk = 0; kk < 16; ++kk) {
      float a[4], b[4];
#pragma unroll
      for (int i = 0; i < 4; ++i) a[i] = As[kk][ty * 4 + i];
#pragma unroll
      for (int j = 0; j < 4; ++j) b[j] = Bs[kk][tx * 4 + j];
#pragma unroll
      for (int i = 0; i < 4; ++i)
#pragma unroll
        for (int j = 0; j < 4; ++j) acc[i][j] += a[i] * b[j];
    }
    __syncthreads();
  }
#pragma unroll
  for (int i = 0; i < 4; ++i) {
    long r = row0 + ty * 4 + i;
#pragma unroll
    for (int j = 0; j < 4; ++j) {
      long c = col0 + tx * 4 + j;
      C[r * ldc + c] = acc[i][j] + bias[c];
    }
  }
}

// bf16 MFMA GEMM: C[M,N] = A[M,K] @ B[N,K]^T (+bias). 128x128 tile, BK=32.
template <typename CT>
__global__ __launch_bounds__(256) void gemm_bf16(
    const short* __restrict__ A, long lda,
    const short* __restrict__ Bw, long ldb,
    const float* __restrict__ bias,
    CT* __restrict__ C, long ldc, int K)
{
  __shared__ short As[128 * 32];
  __shared__ short Bs[128 * 32];
  const int tid = threadIdx.x;
  const long row0 = (long)blockIdx.y * 128;
  const long col0 = (long)blockIdx.x * 128;
  const int wave = tid >> 6, lane = tid & 63;
  const int wm = (wave & 1) * 64, wn = (wave >> 1) * 64;
  const int r16 = lane & 15, quad = lane >> 4;
  f4v acc[4][4] = {};

  for (int k0 = 0; k0 < K; k0 += 32) {
#pragma unroll
    for (int r = 0; r < 2; ++r) {
      int idx = r * 256 + tid;
      int m = idx >> 2;
      int k8 = (idx & 3) * 8;
      __builtin_amdgcn_global_load_lds(
          (const __attribute__((address_space(1))) void*)(A + (row0 + m) * lda + k0 + k8),
          (__attribute__((address_space(3))) void*)(As + idx * 8), 16, 0, 0);
      __builtin_amdgcn_global_load_lds(
          (const __attribute__((address_space(1))) void*)(Bw + (col0 + m) * ldb + k0 + k8),
          (__attribute__((address_space(3))) void*)(Bs + idx * 8), 16, 0, 0);
    }
    __syncthreads();
    s8v af[4], bf[4];
#pragma unroll
    for (int i = 0; i < 4; ++i)
      af[i] = *(const s8v*)&As[(wm + i * 16 + r16) * 32 + quad * 8];
#pragma unroll
    for (int j = 0; j < 4; ++j)
      bf[j] = *(const s8v*)&Bs[(wn + j * 16 + r16) * 32 + quad * 8];
#pragma unroll
    for (int i = 0; i < 4; ++i)
#pragma unroll
      for (int j = 0; j < 4; ++j)
        acc[i][j] = __builtin_amdgcn_mfma_f32_16x16x32_bf16(af[i], bf[j], acc[i][j], 0, 0, 0);
    __syncthreads();
  }

#pragma unroll
  for (int i = 0; i < 4; ++i) {
    long rbase = row0 + wm + i * 16 + quad * 4;
#pragma unroll
    for (int j = 0; j < 4; ++j) {
      long c = col0 + wn + j * 16 + r16;
      float bv = bias ? bias[c] : 0.f;
#pragma unroll
      for (int rg = 0; rg < 4; ++rg)
        stc(&C[(rbase + rg) * ldc + c], acc[i][j][rg] + bv);
    }
  }
}

// ---- Fused GRU step: hg = h_prev @ whh^T + bhh for all 3 gates, then gate.
// Block: 64 rows x 128 cols x 3 gates. Grid: (H/128=4, B/64=64) = 256 blocks.
// Per wave: 32 cols (2 frag-cols) x 64 rows (4 frag-rows) x 3 gates = 24 frags.
__global__ __launch_bounds__(256) void gru_fused(
    const short* __restrict__ Aprev,  // (B,H) bf16 h_{t-1}
    const short* __restrict__ Whh,    // (3H,H) bf16
    const float* __restrict__ bhh,    // (3H)
    const float* __restrict__ xg,     // (B,3H) fp32
    float* __restrict__ h,            // (B,H) fp32 master (in/out)
    short* __restrict__ hout)         // (B,H) bf16 history slice
{
  __shared__ short As[64 * 32];    // 4 KB
  __shared__ short Bs[384 * 32];   // 24 KB
  const int tid = threadIdx.x;
  const long row0 = (long)blockIdx.y * 64;
  const int col0 = blockIdx.x * 128;
  const int wave = tid >> 6, lane = tid & 63;
  const int wn = wave * 32;
  const int r16 = lane & 15, quad = lane >> 4;

  f4v acc[3][4][2] = {};   // [gate][frag-row][frag-col]

  for (int k0 = 0; k0 < H_; k0 += 32) {
    {
      int idx = tid;                      // A tile: 64x32 = 1 iter
      int m = idx >> 2, k8 = (idx & 3) * 8;
      __builtin_amdgcn_global_load_lds(
          (const __attribute__((address_space(1))) void*)(Aprev + (row0 + m) * H_ + k0 + k8),
          (__attribute__((address_space(3))) void*)(As + idx * 8), 16, 0, 0);
    }
#pragma unroll
    for (int r = 0; r < 6; ++r) {         // B tile: 384x32 = 6 iters
      int idx = r * 256 + tid;
      int m = idx >> 2, k8 = (idx & 3) * 8;
      int g = m >> 7, cc = m & 127;
      __builtin_amdgcn_global_load_lds(
          (const __attribute__((address_space(1))) void*)(Whh + ((long)g * H_ + col0 + cc) * H_ + k0 + k8),
          (__attribute__((address_space(3))) void*)(Bs + idx * 8), 16, 0, 0);
    }
    __syncthreads();
    s8v af[4], bf[3][2];
#pragma unroll
    for (int i = 0; i < 4; ++i)
      af[i] = *(const s8v*)&As[(i * 16 + r16) * 32 + quad * 8];
#pragma unroll
    for (int g = 0; g < 3; ++g)
#pragma unroll
      for (int jj = 0; jj < 2; ++jj)
        bf[g][jj] = *(const s8v*)&Bs[(g * 128 + wn + jj * 16 + r16) * 32 + quad * 8];
#pragma unroll
    for (int g = 0; g < 3; ++g)
#pragma unroll
      for (int i = 0; i < 4; ++i)
#pragma unroll
        for (int jj = 0; jj < 2; ++jj)
          acc[g][i][jj] = __builtin_amdgcn_mfma_f32_16x16x32_bf16(af[i], bf[g][jj], acc[g][i][jj], 0, 0, 0);
    __syncthreads();
  }

  // Epilogue: gate math. C/D layout: col=lane&15, row=quad*4+reg.
#pragma unroll
  for (int i = 0; i < 4; ++i) {
#pragma unroll
    for (int jj = 0; jj < 2; ++jj) {
      int col = col0 + wn + jj * 16 + r16;
      float br = bhh[col], bz = bhh[col + 512], bn = bhh[col + 1024];
#pragma unroll
      for (int rg = 0; rg < 4; ++rg) {
        long row = row0 + i * 16 + quad * 4 + rg;
        long gx = row * H3_ + col;
        float hr = acc[0][i][jj][rg] + br;
        float hz = acc[1][i][jj][rg] + bz;
        float hn = acc[2][i][jj][rg] + bn;
        float r = sigmoid_(xg[gx] + hr);
        float z = sigmoid_(xg[gx + 512] + hz);
        float n = tanh_(xg[gx + 1024] + r * hn);
        long hi = row * H_ + col;
        float hv = (1.f - z) * n + z * h[hi];
        h[hi] = hv;
        hout[hi] = f2bf(hv);
      }
    }
  }
}

// ---- batched out_seq: one block per b; LDS-tile all 10 enc-l and 10 dec-t.
__global__ __launch_bounds__(256) void out_seq_all(
    const short* __restrict__ ew3,   // (Lenc, B, W) bf16
    const short* __restrict__ a4,    // (Ldec, B, W) bf16
    const float* __restrict__ v2,
    float* __restrict__ out)
{
  __shared__ short se[L_ * W_];   // 10 KB
  __shared__ short sa[L_ * W_];   // 10 KB
  __shared__ float sv[W_];        // 2 KB
  const int b = blockIdx.x;
  const int tid = threadIdx.x;
  for (int i = tid; i < L_ * W_ / 8; i += 256) {
    int l = i >> 6, c = i & 63;
    *(s8v*)(se + i * 8) = *(const s8v*)(ew3 + ((long)l * B_ + b) * W_ + c * 8);
    *(s8v*)(sa + i * 8) = *(const s8v*)(a4 + ((long)l * B_ + b) * W_ + c * 8);
  }
  for (int i = tid; i < W_; i += 256) sv[i] = v2[i];
  __syncthreads();

  const int wave = tid >> 6, lane = tid & 63;
#pragma unroll
  for (int pp = 0; pp < 25; ++pp) {
    int p = wave * 25 + pp;       // 100 (t,l) pairs over 4 waves
    int t = p / L_, l = p - t * L_;
    s8v ev = *(const s8v*)(se + l * W_ + lane * 8);
    s8v av = *(const s8v*)(sa + t * W_ + lane * 8);
    float acc = 0.f;
#pragma unroll
    for (int j = 0; j < 8; ++j)
      acc += tanh_(bf2f(ev[j]) + bf2f(av[j])) * sv[lane * 8 + j];
#pragma unroll
    for (int off = 32; off; off >>= 1) acc += __shfl_down(acc, off, 64);
    if (lane == 0) out[((long)b * L_ + t) * L_ + l] = acc;
  }
}

// ---- batched out_ori: one wave per (b,t); lanes split k. ----
__global__ __launch_bounds__(256) void out_ori_all(
    const short* __restrict__ dh,    // (Ldec, B, H) bf16
    const float* __restrict__ wori, const float* __restrict__ bori,
    float* __restrict__ out)
{
  int wid = (blockIdx.x * 256 + threadIdx.x) >> 6;   // b*L + t, exactly B*L waves
  int lane = threadIdx.x & 63;
  int b = wid / L_, t = wid - b * L_;
  s8v hv = *(const s8v*)(dh + ((long)t * B_ + b) * H_ + lane * 8);
  float hf[8];
#pragma unroll
  for (int j = 0; j < 8; ++j) hf[j] = bf2f(hv[j]);
  float res[6];
#pragma unroll
  for (int o = 0; o < 6; ++o) {
    const float* wr = wori + (long)o * H3_ + H_ + lane * 8;
    float acc = 0.f;
#pragma unroll
    for (int j = 0; j < 8; ++j) acc += hf[j] * wr[j];
#pragma unroll
    for (int off = 32; off; off >>= 1) acc += __shfl_down(acc, off, 64);
    res[o] = acc;
  }
  if (lane == 0) {
    float* po = out + ORI_BASE + ((long)b * L_ + t) * 6;
#pragma unroll
    for (int o = 0; o < 6; ++o) po[o] = res[o] + bori[o];
  }
}

extern "C" void kernel_launch(void* const* d_in, const int* in_sizes, int n_in,
                              void* d_out, int out_size, void* d_ws, size_t ws_size,
                              hipStream_t stream)
{
  const float* items   = (const float*)d_in[0];
  const float* dec_in  = (const float*)d_in[1];
  const float* emb_w   = (const float*)d_in[2];
  const float* emb_b   = (const float*)d_in[3];
  const float* enc_wih = (const float*)d_in[4];
  const float* enc_whh = (const float*)d_in[5];
  const float* enc_bih = (const float*)d_in[6];
  const float* enc_bhh = (const float*)d_in[7];
  const float* dec_wih = (const float*)d_in[8];
  const float* dec_whh = (const float*)d_in[9];
  const float* dec_bih = (const float*)d_in[10];
  const float* dec_bhh = (const float*)d_in[11];
  const float* w3      = (const float*)d_in[14];
  const float* w4      = (const float*)d_in[15];
  const float* v2      = (const float*)d_in[20];
  const float* wori    = (const float*)d_in[23];
  const float* bori    = (const float*)d_in[24];
  float* out = (float*)d_out;

  // Workspace (~206 MiB of 256 MiB):
  char* ws = (char*)d_ws;
  size_t off = 0;
  auto alloc = [&](size_t bytes) { size_t o = off; off += (bytes + 255) & ~255UL; return o; };
  float* Wc       = (float*)(ws + alloc(H3_ * IN_ * 4));
  float* bc       = (float*)(ws + alloc(H3_ * 4));
  float* h        = (float*)(ws + alloc((size_t)B_ * H_ * 4));           // 8 MiB
  float* xg       = (float*)(ws + alloc((size_t)B_ * H3_ * 4));          // 24 MiB
  short* enc_hist = (short*)(ws + alloc((size_t)11 * B_ * H_ * 2));      // 44 MiB
  short* dec_hist = (short*)(ws + alloc((size_t)L_ * B_ * H_ * 2));      // 40 MiB
  short* ew3      = (short*)(ws + alloc((size_t)L_ * B_ * W_ * 2));      // 40 MiB
  short* a4       = (short*)(ws + alloc((size_t)L_ * B_ * W_ * 2));      // 40 MiB
  short* whh_e    = (short*)(ws + alloc((size_t)H3_ * H_ * 2));
  short* whh_d    = (short*)(ws + alloc((size_t)H3_ * H_ * 2));
  short* wih_d    = (short*)(ws + alloc((size_t)H3_ * H_ * 2));
  short* w3b      = (short*)(ws + alloc((size_t)W_ * H_ * 2));
  short* w4b      = (short*)(ws + alloc((size_t)W_ * H_ * 2));
  short* decb     = (short*)(ws + alloc((size_t)B_ * H_ * 2));           // 4 MiB

  // ---- conversions + weight prep ----
  f2bf_k<<<(H3_ * H_ + 255) / 256, 256, 0, stream>>>(enc_whh, whh_e, H3_ * H_);
  f2bf_k<<<(H3_ * H_ + 255) / 256, 256, 0, stream>>>(dec_whh, whh_d, H3_ * H_);
  f2bf_k<<<(H3_ * H_ + 255) / 256, 256, 0, stream>>>(dec_wih, wih_d, H3_ * H_);
  f2bf_k<<<(W_ * H_ + 255) / 256, 256, 0, stream>>>(w3, w3b, W_ * H_);
  f2bf_k<<<(W_ * H_ + 255) / 256, 256, 0, stream>>>(w4, w4b, W_ * H_);
  f2bf_k<<<(B_ * H_ + 255) / 256, 256, 0, stream>>>(dec_in, decb, B_ * H_);
  build_wc<<<(H3_ * 9 + 255) / 256, 256, 0, stream>>>(
      enc_wih, emb_w, emb_b, enc_bih, Wc, bc);

  hipMemsetAsync(h, 0, (size_t)B_ * H_ * 4, stream);             // h0 = 0
  hipMemsetAsync(enc_hist, 0, (size_t)B_ * H_ * 2, stream);      // slice 0 = 0

  // ---- Encoder recurrence: per step only xg-GEMM + fused GRU ----
  for (int t = 0; t < L_; ++t) {
    gemm_nt<<<dim3(24, 64), 256, 0, stream>>>(
        items, (long)L_ * IN_, (long)t * IN_, Wc, bc, xg, H3_, IN_);
    gru_fused<<<dim3(4, 64), 256, 0, stream>>>(
        enc_hist + (size_t)t * B_ * H_, whh_e, enc_bhh, xg, h,
        enc_hist + (size_t)(t + 1) * B_ * H_);
  }

  // xg_dec = dec_in @ dec_wih^T + dec_bih (fixed across decoder steps)
  gemm_bf16<float><<<dim3(12, 32), 256, 0, stream>>>(
      decb, H_, wih_d, H_, dec_bih, xg, H3_, H_);

  // ---- Decoder recurrence: fused GRU only ----
  for (int t = 0; t < L_; ++t) {
    const short* prev = (t == 0) ? enc_hist + (size_t)10 * B_ * H_
                                 : dec_hist + (size_t)(t - 1) * B_ * H_;
    gru_fused<<<dim3(4, 64), 256, 0, stream>>>(
        prev, whh_d, dec_bhh, xg, h, dec_hist + (size_t)t * B_ * H_);
  }

  // ---- Batched epilogue ----
  // ew3 (t-major): (10*B, W) = enc_hist[1..10] @ w3^T
  gemm_bf16<short><<<dim3(4, 320), 256, 0, stream>>>(
      enc_hist + (size_t)B_ * H_, H_, w3b, H_, nullptr, ew3, W_, H_);
  // a4 (t-major): (10*B, W) = dec_hist @ w4^T
  gemm_bf16<short><<<dim3(4, 320), 256, 0, stream>>>(
      dec_hist, H_, w4b, H_, nullptr, a4, W_, H_);
  out_seq_all<<<B_, 256, 0, stream>>>(ew3, a4, v2, out);
  out_ori_all<<<(B_ * L_) / 4, 256, 0, stream>>>(dec_hist, wori, bori, out);
}

// Round 6
// 701.887 us; speedup vs baseline: 5.5703x; 1.5829x over previous
//
#include <hip/hip_runtime.h>
#include <hip/hip_bf16.h>

// PointerNetwork: B=4096, L=10, IN=8, H=512, W=512. fp32 in/out, ws=256MiB.
// log_softmax over size-1 axes => hi==he==0. Surviving compute:
//   enc GRU, ew3 = h_enc @ w3^T, dec GRU, a4 = h_dec @ w4^T,
//   out_seq = tanh(ew3+a4)@v2, out_ori = h_dec @ wori[:,H:2H]^T + bori.
// Round 6: fast exp2/rcp transcendentals (no fp32 div); encoder xg (K=8)
// fused into GRU epilogue; GRU tiles 64x64x3g at 2 blocks/CU; wave-parallel
// build_wc. ~33 dispatches.

#define B_   4096
#define L_   10
#define IN_  8
#define H_   512
#define H3_  1536
#define W_   512
#define ORI_BASE (B_ * L_ * L_)   // 409600

typedef __attribute__((ext_vector_type(8))) short s8v;
typedef __attribute__((ext_vector_type(4))) float f4v;

#define LOG2E  1.4426950408889634f
#define LOG2E2 2.8853900817779268f

__device__ __forceinline__ float sig_fast(float x) {
  float e = __builtin_amdgcn_exp2f(-x * LOG2E);
  return __builtin_amdgcn_rcpf(1.f + e);
}
__device__ __forceinline__ float tanh_fast(float x) {
  float e = __builtin_amdgcn_exp2f(x * LOG2E2);
  return 1.f - 2.f * __builtin_amdgcn_rcpf(e + 1.f);
}
__device__ __forceinline__ short f2bf(float f) {
  __hip_bfloat16 h = __float2bfloat16(f);
  return __builtin_bit_cast(short, h);
}
__device__ __forceinline__ float bf2f(short s) {
  __hip_bfloat16 h = __builtin_bit_cast(__hip_bfloat16, s);
  return __bfloat162float(h);
}
__device__ __forceinline__ void stc(float* p, float v) { *p = v; }
__device__ __forceinline__ void stc(short* p, float v) { *p = f2bf(v); }

__global__ __launch_bounds__(256) void f2bf_k(const float* __restrict__ src,
                                              short* __restrict__ dst, int n)
{
  int i = blockIdx.x * 256 + threadIdx.x;
  if (i < n) dst[i] = f2bf(src[i]);
}

// Fold embedding into encoder input weight. One wave per g-row (1536 waves).
// Wc[g][j] = sum_k enc_wih[g,k]*emb_w[k,j]; bc[g] = sum_k enc_wih[g,k]*emb_b[k] + enc_bih[g].
__global__ __launch_bounds__(256) void build_wc(
    const float* __restrict__ enc_wih, const float* __restrict__ emb_w,
    const float* __restrict__ emb_b, const float* __restrict__ enc_bih,
    float* __restrict__ Wc, float* __restrict__ bc)
{
  __shared__ float se[H_ * IN_];   // 16 KB
  __shared__ float sb[H_];         // 2 KB
  const int tid = threadIdx.x;
  for (int i = tid; i < H_ * IN_; i += 256) se[i] = emb_w[i];
  for (int i = tid; i < H_; i += 256) sb[i] = emb_b[i];
  __syncthreads();
  int g = (blockIdx.x * 256 + tid) >> 6;   // 4 waves/block, 384 blocks
  int lane = tid & 63;
  const float* wr = enc_wih + (long)g * H_ + lane * 8;
  float w8[8];
#pragma unroll
  for (int j = 0; j < 8; ++j) w8[j] = wr[j];
  float acc[9] = {};
#pragma unroll
  for (int kk = 0; kk < 8; ++kk) {
    int k = lane * 8 + kk;
#pragma unroll
    for (int j = 0; j < 8; ++j) acc[j] += w8[kk] * se[k * IN_ + j];
    acc[8] += w8[kk] * sb[k];
  }
#pragma unroll
  for (int j = 0; j < 9; ++j)
#pragma unroll
    for (int off = 32; off; off >>= 1) acc[j] += __shfl_down(acc[j], off, 64);
  if (lane == 0) {
#pragma unroll
    for (int j = 0; j < 8; ++j) Wc[g * IN_ + j] = acc[j];
    bc[g] = acc[8] + enc_bih[g];
  }
}

// bf16 MFMA GEMM: C[M,N] = A[M,K] @ B[N,K]^T (+bias). 128x128 tile, BK=32.
template <typename CT>
__global__ __launch_bounds__(256) void gemm_bf16(
    const short* __restrict__ A, long lda,
    const short* __restrict__ Bw, long ldb,
    const float* __restrict__ bias,
    CT* __restrict__ C, long ldc, int K)
{
  __shared__ short As[128 * 32];
  __shared__ short Bs[128 * 32];
  const int tid = threadIdx.x;
  const long row0 = (long)blockIdx.y * 128;
  const long col0 = (long)blockIdx.x * 128;
  const int wave = tid >> 6, lane = tid & 63;
  const int wm = (wave & 1) * 64, wn = (wave >> 1) * 64;
  const int r16 = lane & 15, quad = lane >> 4;
  f4v acc[4][4] = {};

  for (int k0 = 0; k0 < K; k0 += 32) {
#pragma unroll
    for (int r = 0; r < 2; ++r) {
      int idx = r * 256 + tid;
      int m = idx >> 2;
      int k8 = (idx & 3) * 8;
      __builtin_amdgcn_global_load_lds(
          (const __attribute__((address_space(1))) void*)(A + (row0 + m) * lda + k0 + k8),
          (__attribute__((address_space(3))) void*)(As + idx * 8), 16, 0, 0);
      __builtin_amdgcn_global_load_lds(
          (const __attribute__((address_space(1))) void*)(Bw + (col0 + m) * ldb + k0 + k8),
          (__attribute__((address_space(3))) void*)(Bs + idx * 8), 16, 0, 0);
    }
    __syncthreads();
    s8v af[4], bf[4];
#pragma unroll
    for (int i = 0; i < 4; ++i)
      af[i] = *(const s8v*)&As[(wm + i * 16 + r16) * 32 + quad * 8];
#pragma unroll
    for (int j = 0; j < 4; ++j)
      bf[j] = *(const s8v*)&Bs[(wn + j * 16 + r16) * 32 + quad * 8];
#pragma unroll
    for (int i = 0; i < 4; ++i)
#pragma unroll
      for (int j = 0; j < 4; ++j)
        acc[i][j] = __builtin_amdgcn_mfma_f32_16x16x32_bf16(af[i], bf[j], acc[i][j], 0, 0, 0);
    __syncthreads();
  }

#pragma unroll
  for (int i = 0; i < 4; ++i) {
    long rbase = row0 + wm + i * 16 + quad * 4;
#pragma unroll
    for (int j = 0; j < 4; ++j) {
      long c = col0 + wn + j * 16 + r16;
      float bv = bias ? bias[c] : 0.f;
#pragma unroll
      for (int rg = 0; rg < 4; ++rg)
        stc(&C[(rbase + rg) * ldc + c], acc[i][j][rg] + bv);
    }
  }
}

// ---- Fused GRU step. Tile: 64 rows x 64 cols x 3 gates. Grid (8, 64) = 512
// blocks (2/CU). Wave w: cols [w*16, w*16+16), 4 frag-rows, 3 gates.
// ENC: xg computed inline from items (K=8, folded emb weights Wc/bc).
// !ENC: xg read from buffer (B,3H).
template <bool ENC>
__global__ __launch_bounds__(256) void gru_fused(
    const short* __restrict__ Aprev,  // (B,H) bf16 h_{t-1}
    const short* __restrict__ Whh,    // (3H,H) bf16
    const float* __restrict__ bhh,    // (3H)
    const float* __restrict__ xg,     // (B,3H) fp32 (decoder)
    const float* __restrict__ items_t,// encoder: &items[0][t][0], row stride 80
    const float* __restrict__ Wc,     // (3H,8)
    const float* __restrict__ bc,     // (3H)
    float* __restrict__ h,            // (B,H) fp32 master (in/out)
    short* __restrict__ hout)         // (B,H) bf16 history slice
{
  __shared__ short As[64 * 32];    // 4 KB (reused for items in ENC epilogue)
  __shared__ short Bs[192 * 32];   // 12 KB
  const int tid = threadIdx.x;
  const long row0 = (long)blockIdx.y * 64;
  const int col0 = blockIdx.x * 64;
  const int wave = tid >> 6, lane = tid & 63;
  const int r16 = lane & 15, quad = lane >> 4;

  f4v acc[3][4] = {};   // [gate][frag-row]

  for (int k0 = 0; k0 < H_; k0 += 32) {
    {
      int m = tid >> 2, k8 = (tid & 3) * 8;   // A: 64x32, 1 iter
      __builtin_amdgcn_global_load_lds(
          (const __attribute__((address_space(1))) void*)(Aprev + (row0 + m) * H_ + k0 + k8),
          (__attribute__((address_space(3))) void*)(As + tid * 8), 16, 0, 0);
    }
#pragma unroll
    for (int r = 0; r < 3; ++r) {             // B: 192x32, 3 iters
      int idx = r * 256 + tid;
      int m = idx >> 2, k8 = (idx & 3) * 8;
      int g = m >> 6, cc = m & 63;
      __builtin_amdgcn_global_load_lds(
          (const __attribute__((address_space(1))) void*)(Whh + ((long)g * H_ + col0 + cc) * H_ + k0 + k8),
          (__attribute__((address_space(3))) void*)(Bs + idx * 8), 16, 0, 0);
    }
    __syncthreads();
    s8v af[4], bf[3];
#pragma unroll
    for (int i = 0; i < 4; ++i)
      af[i] = *(const s8v*)&As[(i * 16 + r16) * 32 + quad * 8];
#pragma unroll
    for (int g = 0; g < 3; ++g)
      bf[g] = *(const s8v*)&Bs[(g * 64 + wave * 16 + r16) * 32 + quad * 8];
#pragma unroll
    for (int g = 0; g < 3; ++g)
#pragma unroll
      for (int i = 0; i < 4; ++i)
        acc[g][i] = __builtin_amdgcn_mfma_f32_16x16x32_bf16(af[i], bf[g], acc[g][i], 0, 0, 0);
    __syncthreads();
  }

  // Column owned by this thread (C/D layout: col=lane&15, row=quad*4+reg).
  const int col = col0 + wave * 16 + r16;
  float wc[3][8], bcv[3];
  if (ENC) {
#pragma unroll
    for (int g = 0; g < 3; ++g) {
      const float* wr = Wc + ((long)g * H_ + col) * IN_;
#pragma unroll
      for (int j = 0; j < 8; ++j) wc[g][j] = wr[j];
      bcv[g] = bc[g * H_ + col];
    }
    // stage items rows into LDS (reuse As): 64 rows x 8 fp32
    float* itemS = (float*)As;
    int i2 = tid * 2;
    int m = i2 >> 3, j = i2 & 7;
    itemS[i2] = items_t[(row0 + m) * (L_ * IN_) + j];
    itemS[i2 + 1] = items_t[(row0 + m) * (L_ * IN_) + j + 1];
    __syncthreads();
  }
  float bhr = bhh[col], bhz = bhh[col + H_], bhn = bhh[col + 2 * H_];

#pragma unroll
  for (int i = 0; i < 4; ++i) {
#pragma unroll
    for (int rg = 0; rg < 4; ++rg) {
      int rl = i * 16 + quad * 4 + rg;
      long row = row0 + rl;
      float xr, xz, xn;
      if (ENC) {
        const float* it = (const float*)As + rl * 8;
        xr = bcv[0]; xz = bcv[1]; xn = bcv[2];
#pragma unroll
        for (int j = 0; j < 8; ++j) {
          float iv = it[j];
          xr += iv * wc[0][j];
          xz += iv * wc[1][j];
          xn += iv * wc[2][j];
        }
      } else {
        long gx = row * H3_ + col;
        xr = xg[gx]; xz = xg[gx + H_]; xn = xg[gx + 2 * H_];
      }
      float r = sig_fast(xr + acc[0][i][rg] + bhr);
      float z = sig_fast(xz + acc[1][i][rg] + bhz);
      float n = tanh_fast(xn + r * (acc[2][i][rg] + bhn));
      long hi = row * H_ + col;
      float hv = (1.f - z) * n + z * h[hi];
      h[hi] = hv;
      hout[hi] = f2bf(hv);
    }
  }
}

// ---- batched out_seq: one block per b; LDS-tile 10 enc-l + 10 dec-t rows.
__global__ __launch_bounds__(256) void out_seq_all(
    const short* __restrict__ ew3,   // (Lenc, B, W) bf16
    const short* __restrict__ a4,    // (Ldec, B, W) bf16
    const float* __restrict__ v2,
    float* __restrict__ out)
{
  __shared__ short se[L_ * W_];   // 10 KB
  __shared__ short sa[L_ * W_];   // 10 KB
  __shared__ float sv[W_];        // 2 KB
  const int b = blockIdx.x;
  const int tid = threadIdx.x;
  for (int i = tid; i < L_ * W_ / 8; i += 256) {
    int l = i >> 6, c = i & 63;
    *(s8v*)(se + i * 8) = *(const s8v*)(ew3 + ((long)l * B_ + b) * W_ + c * 8);
    *(s8v*)(sa + i * 8) = *(const s8v*)(a4 + ((long)l * B_ + b) * W_ + c * 8);
  }
  for (int i = tid; i < W_; i += 256) sv[i] = v2[i];
  __syncthreads();

  const int wave = tid >> 6, lane = tid & 63;
#pragma unroll
  for (int pp = 0; pp < 25; ++pp) {
    int p = wave * 25 + pp;       // 100 (t,l) pairs over 4 waves
    int t = p / L_, l = p - t * L_;
    s8v ev = *(const s8v*)(se + l * W_ + lane * 8);
    s8v av = *(const s8v*)(sa + t * W_ + lane * 8);
    float acc = 0.f;
#pragma unroll
    for (int j = 0; j < 8; ++j)
      acc += tanh_fast(bf2f(ev[j]) + bf2f(av[j])) * sv[lane * 8 + j];
#pragma unroll
    for (int off = 32; off; off >>= 1) acc += __shfl_down(acc, off, 64);
    if (lane == 0) out[((long)b * L_ + t) * L_ + l] = acc;
  }
}

// ---- batched out_ori: one wave per (b,t). ----
__global__ __launch_bounds__(256) void out_ori_all(
    const short* __restrict__ dh,    // (Ldec, B, H) bf16
    const float* __restrict__ wori, const float* __restrict__ bori,
    float* __restrict__ out)
{
  int wid = (blockIdx.x * 256 + threadIdx.x) >> 6;   // b*L + t
  int lane = threadIdx.x & 63;
  int b = wid / L_, t = wid - b * L_;
  s8v hv = *(const s8v*)(dh + ((long)t * B_ + b) * H_ + lane * 8);
  float hf[8];
#pragma unroll
  for (int j = 0; j < 8; ++j) hf[j] = bf2f(hv[j]);
  float res[6];
#pragma unroll
  for (int o = 0; o < 6; ++o) {
    const float* wr = wori + (long)o * H3_ + H_ + lane * 8;
    float acc = 0.f;
#pragma unroll
    for (int j = 0; j < 8; ++j) acc += hf[j] * wr[j];
#pragma unroll
    for (int off = 32; off; off >>= 1) acc += __shfl_down(acc, off, 64);
    res[o] = acc;
  }
  if (lane == 0) {
    float* po = out + ORI_BASE + ((long)b * L_ + t) * 6;
#pragma unroll
    for (int o = 0; o < 6; ++o) po[o] = res[o] + bori[o];
  }
}

extern "C" void kernel_launch(void* const* d_in, const int* in_sizes, int n_in,
                              void* d_out, int out_size, void* d_ws, size_t ws_size,
                              hipStream_t stream)
{
  const float* items   = (const float*)d_in[0];
  const float* dec_in  = (const float*)d_in[1];
  const float* emb_w   = (const float*)d_in[2];
  const float* emb_b   = (const float*)d_in[3];
  const float* enc_wih = (const float*)d_in[4];
  const float* enc_whh = (const float*)d_in[5];
  const float* enc_bih = (const float*)d_in[6];
  const float* enc_bhh = (const float*)d_in[7];
  const float* dec_wih = (const float*)d_in[8];
  const float* dec_whh = (const float*)d_in[9];
  const float* dec_bih = (const float*)d_in[10];
  const float* dec_bhh = (const float*)d_in[11];
  const float* w3      = (const float*)d_in[14];
  const float* w4      = (const float*)d_in[15];
  const float* v2      = (const float*)d_in[20];
  const float* wori    = (const float*)d_in[23];
  const float* bori    = (const float*)d_in[24];
  float* out = (float*)d_out;

  char* ws = (char*)d_ws;
  size_t off = 0;
  auto alloc = [&](size_t bytes) { size_t o = off; off += (bytes + 255) & ~255UL; return o; };
  float* Wc       = (float*)(ws + alloc(H3_ * IN_ * 4));
  float* bc       = (float*)(ws + alloc(H3_ * 4));
  float* h        = (float*)(ws + alloc((size_t)B_ * H_ * 4));           // 8 MiB
  float* xg       = (float*)(ws + alloc((size_t)B_ * H3_ * 4));          // 24 MiB
  short* enc_hist = (short*)(ws + alloc((size_t)11 * B_ * H_ * 2));      // 44 MiB
  short* dec_hist = (short*)(ws + alloc((size_t)L_ * B_ * H_ * 2));      // 40 MiB
  short* ew3      = (short*)(ws + alloc((size_t)L_ * B_ * W_ * 2));      // 40 MiB
  short* a4       = (short*)(ws + alloc((size_t)L_ * B_ * W_ * 2));      // 40 MiB
  short* whh_e    = (short*)(ws + alloc((size_t)H3_ * H_ * 2));
  short* whh_d    = (short*)(ws + alloc((size_t)H3_ * H_ * 2));
  short* wih_d    = (short*)(ws + alloc((size_t)H3_ * H_ * 2));
  short* w3b      = (short*)(ws + alloc((size_t)W_ * H_ * 2));
  short* w4b      = (short*)(ws + alloc((size_t)W_ * H_ * 2));
  short* decb     = (short*)(ws + alloc((size_t)B_ * H_ * 2));           // 4 MiB

  // ---- prep ----
  f2bf_k<<<(H3_ * H_ + 255) / 256, 256, 0, stream>>>(enc_whh, whh_e, H3_ * H_);
  f2bf_k<<<(H3_ * H_ + 255) / 256, 256, 0, stream>>>(dec_whh, whh_d, H3_ * H_);
  f2bf_k<<<(H3_ * H_ + 255) / 256, 256, 0, stream>>>(dec_wih, wih_d, H3_ * H_);
  f2bf_k<<<(W_ * H_ + 255) / 256, 256, 0, stream>>>(w3, w3b, W_ * H_);
  f2bf_k<<<(W_ * H_ + 255) / 256, 256, 0, stream>>>(w4, w4b, W_ * H_);
  f2bf_k<<<(B_ * H_ + 255) / 256, 256, 0, stream>>>(dec_in, decb, B_ * H_);
  build_wc<<<384, 256, 0, stream>>>(enc_wih, emb_w, emb_b, enc_bih, Wc, bc);

  hipMemsetAsync(h, 0, (size_t)B_ * H_ * 4, stream);             // h0 = 0
  hipMemsetAsync(enc_hist, 0, (size_t)B_ * H_ * 2, stream);      // slice 0 = 0

  // ---- Encoder recurrence: single fused kernel per step (xg inline) ----
  for (int t = 0; t < L_; ++t) {
    gru_fused<true><<<dim3(8, 64), 256, 0, stream>>>(
        enc_hist + (size_t)t * B_ * H_, whh_e, enc_bhh, nullptr,
        items + (size_t)t * IN_, Wc, bc, h,
        enc_hist + (size_t)(t + 1) * B_ * H_);
  }

  // xg_dec = dec_in @ dec_wih^T + dec_bih (fixed across decoder steps)
  gemm_bf16<float><<<dim3(12, 32), 256, 0, stream>>>(
      decb, H_, wih_d, H_, dec_bih, xg, H3_, H_);

  // ---- Decoder recurrence ----
  for (int t = 0; t < L_; ++t) {
    const short* prev = (t == 0) ? enc_hist + (size_t)10 * B_ * H_
                                 : dec_hist + (size_t)(t - 1) * B_ * H_;
    gru_fused<false><<<dim3(8, 64), 256, 0, stream>>>(
        prev, whh_d, dec_bhh, xg, nullptr, nullptr, nullptr, h,
        dec_hist + (size_t)t * B_ * H_);
  }

  // ---- Batched epilogue ----
  gemm_bf16<short><<<dim3(4, 320), 256, 0, stream>>>(
      enc_hist + (size_t)B_ * H_, H_, w3b, H_, nullptr, ew3, W_, H_);
  gemm_bf16<short><<<dim3(4, 320), 256, 0, stream>>>(
      dec_hist, H_, w4b, H_, nullptr, a4, W_, H_);
  out_seq_all<<<B_, 256, 0, stream>>>(ew3, a4, v2, out);
  out_ori_all<<<(B_ * L_) / 4, 256, 0, stream>>>(dec_hist, wori, bori, out);
}